// Round 1
// baseline (433.962 us; speedup 1.0000x reference)
//
#include <hip/hip_runtime.h>
#include <hip/hip_fp16.h>

// Sinkhorn OT kernel. n=64, in_size=1024, in_dim=128, heads=4, out_size=64.
// Phase structure:
//   kernel1 (256 WGs x 1024 thr): K-GEMM -> EK=exp(K) in regs (8x8/thread) ->
//            100 multiplicative Sinkhorn iters (eu=(1/16)/(EK.ev), ev=1/(eu^T.EK))
//            -> T = EK*eu*ev stored f16 to d_ws (33.5MB)
//   kernel2 (256 WGs x 512 thr): out[n,o,m*128+d] = sum_i T[i,o]*x[n,i,d]
// Multiplicative domain == reference log-domain (u cancels inside Z; eps=1),
// and values are bounded (|K|<~5) so fp32 is numerically safe.

__device__ __forceinline__ float2 pkfma(float2 a, float2 b, float2 c) {
  return make_float2(fmaf(a.x, b.x, c.x), fmaf(a.y, b.y, c.y));
}

__global__ __launch_bounds__(1024) void sinkhorn_kernel(
    const float* __restrict__ x, const float* __restrict__ w,
    __half* __restrict__ T) {
  const int b = blockIdx.x;   // 256 batches: b = n*4 + m
  const int nb = b >> 2;
  const int m = b & 3;
  const int t = threadIdx.x;
  const int gi = t >> 3;      // 0..127 row group (rows 8*gi..8*gi+7)
  const int gj = t & 7;       // 0..7  col group (cols 8*gj..8*gj+7)

  // LDS union: phases are time-disjoint. pu overlaps pv+pw head but pw is dead
  // by the time pu is rewritten (barrier-ordered).
  __shared__ union LdsU {
    float wt[128][66];                                  // W^T [d][j], pad 66
    float pu[1024][9];                                  // row partials, pad 9
    struct { float pv[128][68]; float pw[16][64]; } s;  // col partials
  } u_;
  __shared__ float eu[1024];
  __shared__ float ev[64];

  // ---- Phase 1a: stage transposed weight for this head ----
  const float* wm = w + (size_t)m * 64 * 128;
  for (int e = t; e < 64 * 128; e += 1024) {
    int j = e >> 7;
    int d = e & 127;
    u_.wt[d][j] = wm[e];
  }
  if (t < 64) ev[t] = 1.0f;
  __syncthreads();

  // ---- Phase 1b: K tile (8 rows x 8 cols per thread), then EK = exp(K) ----
  float2 E2[8][4];  // [row][col-pair]
  #pragma unroll
  for (int r = 0; r < 8; ++r)
    #pragma unroll
    for (int c = 0; c < 4; ++c) E2[r][c] = make_float2(0.f, 0.f);

  const float* xrow = x + (size_t)nb * 1024 * 128 + (size_t)gi * 8 * 128;
  for (int d = 0; d < 128; d += 2) {
    float2 wa[4], wb[4];
    #pragma unroll
    for (int c = 0; c < 4; ++c) {
      wa[c] = *(const float2*)&u_.wt[d][8 * gj + 2 * c];
      wb[c] = *(const float2*)&u_.wt[d + 1][8 * gj + 2 * c];
    }
    #pragma unroll
    for (int r = 0; r < 8; ++r) {
      float2 xv = *(const float2*)&xrow[r * 128 + d];
      #pragma unroll
      for (int c = 0; c < 4; ++c) {
        E2[r][c] = pkfma(make_float2(xv.x, xv.x), wa[c], E2[r][c]);
        E2[r][c] = pkfma(make_float2(xv.y, xv.y), wb[c], E2[r][c]);
      }
    }
  }
  #pragma unroll
  for (int r = 0; r < 8; ++r)
    #pragma unroll
    for (int c = 0; c < 4; ++c) {
      E2[r][c].x = __expf(E2[r][c].x);
      E2[r][c].y = __expf(E2[r][c].y);
    }
  __syncthreads();  // everyone done reading wt before pu overwrites it

  // ---- Phase 2: 100 Sinkhorn iterations (multiplicative domain) ----
  for (int it = 0; it < 100; ++it) {
    // (A) row partial sums: s_i partial over this thread's 8 cols
    float4 e0 = *(const float4*)&ev[8 * gj];
    float4 e1 = *(const float4*)&ev[8 * gj + 4];
    float2 ep[4] = {make_float2(e0.x, e0.y), make_float2(e0.z, e0.w),
                    make_float2(e1.x, e1.y), make_float2(e1.z, e1.w)};
    #pragma unroll
    for (int r = 0; r < 8; ++r) {
      float2 acc = make_float2(0.f, 0.f);
      #pragma unroll
      for (int c = 0; c < 4; ++c) acc = pkfma(E2[r][c], ep[c], acc);
      u_.pu[8 * gi + r][gj] = acc.x + acc.y;
    }
    __syncthreads();
    // (A2) finish row sums, eu_i = (1/16)/s_i
    {
      float ss = 0.f;
      #pragma unroll
      for (int k = 0; k < 8; ++k) ss += u_.pu[t][k];
      eu[t] = 0.0625f / ss;
    }
    __syncthreads();
    // (B) column partial sums over this thread's 8 rows
    float4 v0 = *(const float4*)&eu[8 * gi];
    float4 v1 = *(const float4*)&eu[8 * gi + 4];
    float ur[8] = {v0.x, v0.y, v0.z, v0.w, v1.x, v1.y, v1.z, v1.w};
    float2 tp[4] = {make_float2(0.f, 0.f), make_float2(0.f, 0.f),
                    make_float2(0.f, 0.f), make_float2(0.f, 0.f)};
    #pragma unroll
    for (int r = 0; r < 8; ++r) {
      float2 uu = make_float2(ur[r], ur[r]);
      #pragma unroll
      for (int c = 0; c < 4; ++c) tp[c] = pkfma(E2[r][c], uu, tp[c]);
    }
    *(float4*)&u_.s.pv[gi][8 * gj] =
        make_float4(tp[0].x, tp[0].y, tp[1].x, tp[1].y);
    *(float4*)&u_.s.pv[gi][8 * gj + 4] =
        make_float4(tp[2].x, tp[2].y, tp[3].x, tp[3].y);
    __syncthreads();
    // (B2) reduce 128 gi-groups -> 16
    {
      int j = t & 63, g = t >> 6;
      float ss = 0.f;
      #pragma unroll
      for (int k = 0; k < 8; ++k) ss += u_.s.pv[8 * g + k][j];
      u_.s.pw[g][j] = ss;
    }
    __syncthreads();
    // (B3) final 16 -> ev_j = 1/t_j
    if (t < 64) {
      float ss = 0.f;
      #pragma unroll
      for (int g = 0; g < 16; ++g) ss += u_.s.pw[g][t];
      ev[t] = 1.0f / ss;
    }
    __syncthreads();
  }

  // ---- Phase 3: T = EK * eu_i * ev_j, store f16 ----
  float4 e0 = *(const float4*)&ev[8 * gj];
  float4 e1 = *(const float4*)&ev[8 * gj + 4];
  float2 ep[4] = {make_float2(e0.x, e0.y), make_float2(e0.z, e0.w),
                  make_float2(e1.x, e1.y), make_float2(e1.z, e1.w)};
  float4 v0 = *(const float4*)&eu[8 * gi];
  float4 v1 = *(const float4*)&eu[8 * gi + 4];
  float ur[8] = {v0.x, v0.y, v0.z, v0.w, v1.x, v1.y, v1.z, v1.w};
  __half* Tb = T + (size_t)b * 1024 * 64;
  #pragma unroll
  for (int r = 0; r < 8; ++r) {
    #pragma unroll
    for (int c = 0; c < 4; ++c) {
      float2 tv;
      tv.x = E2[r][c].x * ur[r] * ep[c].x;
      tv.y = E2[r][c].y * ur[r] * ep[c].y;
      __half2 h = __float22half2_rn(tv);
      *(__half2*)&Tb[(size_t)(8 * gi + r) * 64 + 8 * gj + 2 * c] = h;
    }
  }
}

// out[n][o][m*128+d] = sum_i T[b][i][o] * x[n][i][d]
__global__ __launch_bounds__(512) void output_kernel(
    const float* __restrict__ x, const __half* __restrict__ T,
    float* __restrict__ out) {
  const int b = blockIdx.x;
  const int nb = b >> 2;
  const int m = b & 3;
  const int t = threadIdx.x;
  const int og = t & 15;         // o = 4*og + oc
  const int db = (t >> 4) & 15;  // d = 8*db + ...
  const int s = t >> 8;          // i-half split

  __shared__ float Tl[64][68];
  __shared__ float Xl[64][132];

  float2 acc[4][4];
  #pragma unroll
  for (int oc = 0; oc < 4; ++oc)
    #pragma unroll
    for (int dp = 0; dp < 4; ++dp) acc[oc][dp] = make_float2(0.f, 0.f);

  const __half* Tb = T + (size_t)b * 1024 * 64;
  const float* xb = x + (size_t)nb * 1024 * 128;

  for (int ch = 0; ch < 16; ++ch) {
    __syncthreads();
    for (int e = t; e < 64 * 64; e += 512) {
      int i = e >> 6, j = e & 63;
      Tl[i][j] = __half2float(Tb[(size_t)(64 * ch + i) * 64 + j]);
    }
    for (int e = t; e < 64 * 128; e += 512) {
      int i = e >> 7, d = e & 127;
      Xl[i][d] = xb[(size_t)(64 * ch + i) * 128 + d];
    }
    __syncthreads();
    const int i0 = 32 * s;
    #pragma unroll 4
    for (int i = i0; i < i0 + 32; ++i) {
      float4 tv = *(const float4*)&Tl[i][4 * og];
      float4 x0 = *(const float4*)&Xl[i][8 * db];
      float4 x1 = *(const float4*)&Xl[i][8 * db + 4];
      float to[4] = {tv.x, tv.y, tv.z, tv.w};
      float2 xp[4] = {make_float2(x0.x, x0.y), make_float2(x0.z, x0.w),
                      make_float2(x1.x, x1.y), make_float2(x1.z, x1.w)};
      #pragma unroll
      for (int oc = 0; oc < 4; ++oc)
        #pragma unroll
        for (int dp = 0; dp < 4; ++dp)
          acc[oc][dp] = pkfma(make_float2(to[oc], to[oc]), xp[dp], acc[oc][dp]);
    }
  }
  // merge s=1 into s=0 via LDS, then store
  __syncthreads();
  float2* mbuf = (float2*)&Xl[0][0];  // 256*16 float2 = 32KB, fits in Xl
  if (s == 1) {
    #pragma unroll
    for (int oc = 0; oc < 4; ++oc)
      #pragma unroll
      for (int dp = 0; dp < 4; ++dp)
        mbuf[(size_t)(t - 256) * 16 + oc * 4 + dp] = acc[oc][dp];
  }
  __syncthreads();
  if (s == 0) {
    #pragma unroll
    for (int oc = 0; oc < 4; ++oc) {
      float2 p0 = mbuf[(size_t)t * 16 + oc * 4 + 0];
      float2 p1 = mbuf[(size_t)t * 16 + oc * 4 + 1];
      float2 p2 = mbuf[(size_t)t * 16 + oc * 4 + 2];
      float2 p3 = mbuf[(size_t)t * 16 + oc * 4 + 3];
      int o = 4 * og + oc;
      float* op = out + ((size_t)nb * 64 + o) * 512 + m * 128 + 8 * db;
      float4 o0 = make_float4(acc[oc][0].x + p0.x, acc[oc][0].y + p0.y,
                              acc[oc][1].x + p1.x, acc[oc][1].y + p1.y);
      float4 o1 = make_float4(acc[oc][2].x + p2.x, acc[oc][2].y + p2.y,
                              acc[oc][3].x + p3.x, acc[oc][3].y + p3.y);
      *(float4*)op = o0;
      *(float4*)(op + 4) = o1;
    }
  }
}

extern "C" void kernel_launch(void* const* d_in, const int* in_sizes, int n_in,
                              void* d_out, int out_size, void* d_ws, size_t ws_size,
                              hipStream_t stream) {
  const float* x = (const float*)d_in[0];   // [64][1024][128] fp32
  const float* w = (const float*)d_in[1];   // [4][64][128] fp32
  float* out = (float*)d_out;               // [64][64][512] fp32
  __half* T = (__half*)d_ws;                // 256*1024*64 f16 = 33.5 MB scratch
  sinkhorn_kernel<<<256, 1024, 0, stream>>>(x, w, T);
  output_kernel<<<256, 512, 0, stream>>>(x, T, out);
}

// Round 2
// 362.724 us; speedup vs baseline: 1.1964x; 1.1964x over previous
//
#include <hip/hip_runtime.h>
#include <hip/hip_fp16.h>

// Sinkhorn OT. n=64, in_size=1024, in_dim=128, heads=4, out_size=64.
// kernel1: K-GEMM -> EK=exp(K) in regs (8x8/thread) -> 100 multiplicative
//   Sinkhorn iters with DPP/swizzle cross-lane reductions (2 barriers/iter)
//   -> T=EK*eu*ev stored f16 to d_ws.
// kernel2: out = T^T x per batch, global_load_lds double-buffered.

__device__ __forceinline__ float2 pkfma(float2 a, float2 b, float2 c) {
  return make_float2(fmaf(a.x, b.x, c.x), fmaf(a.y, b.y, c.y));
}

// v + dpp_permuted(v). CTRL: 0xB1 quad xor1, 0x4E quad xor2,
// 0x141 row_half_mirror (xor4 after xor1+xor2), 0x128 row_ror:8 (xor8 in 16).
template <int CTRL>
__device__ __forceinline__ float dpp_add(float v) {
  return v + __int_as_float(__builtin_amdgcn_update_dpp(
                 0, __float_as_int(v), CTRL, 0xf, 0xf, true));
}
// v + lane(xor16) within 32-lane halves.
__device__ __forceinline__ float swz16_add(float v) {
  return v + __int_as_float(
                 __builtin_amdgcn_ds_swizzle(__float_as_int(v), 0x401F));
}

__device__ __forceinline__ void gll16(const void* gsrc, void* ldst) {
  __builtin_amdgcn_global_load_lds(
      (const __attribute__((address_space(1))) void*)gsrc,
      (__attribute__((address_space(3))) void*)ldst, 16, 0, 0);
}

__global__ __launch_bounds__(1024, 4) void sinkhorn_kernel(
    const float* __restrict__ x, const float* __restrict__ w,
    __half* __restrict__ T) {
  const int b = blockIdx.x;  // 256: b = n*4 + m
  const int nb = b >> 2;
  const int m = b & 3;
  const int t = threadIdx.x;
  const int gi = t >> 3;  // 0..127: rows 8*gi..8*gi+7
  const int gj = t & 7;   // 0..7 : cols 8*gj..8*gj+7
  const int lane = t & 63;

  __shared__ union {
    float wt[128][68];  // phase 1 only (pad 68: 16B-aligned rows)
    float cw[32][64];   // per-half-wave column partials
  } u_;
  __shared__ float ev[64];

  // ---- Phase 1a: stage W^T for this head ----
  const float* wm = w + (size_t)m * 64 * 128;
  for (int e = t; e < 64 * 128; e += 1024) {
    int j = e >> 7, d = e & 127;
    u_.wt[d][j] = wm[e];
  }
  if (t < 64) ev[t] = 1.0f;
  __syncthreads();

  // ---- Phase 1b: K tile (8x8 per thread), then EK = exp(K) ----
  float2 E2[8][4];  // [row][col-pair]
  #pragma unroll
  for (int r = 0; r < 8; ++r)
    #pragma unroll
    for (int c = 0; c < 4; ++c) E2[r][c] = make_float2(0.f, 0.f);

  const float* xrow = x + (size_t)nb * 1024 * 128 + (size_t)gi * 8 * 128;
  for (int d = 0; d < 128; d += 2) {
    float4 wA0 = *(const float4*)&u_.wt[d][8 * gj];
    float4 wA1 = *(const float4*)&u_.wt[d][8 * gj + 4];
    float4 wB0 = *(const float4*)&u_.wt[d + 1][8 * gj];
    float4 wB1 = *(const float4*)&u_.wt[d + 1][8 * gj + 4];
    float2 wa[4] = {make_float2(wA0.x, wA0.y), make_float2(wA0.z, wA0.w),
                    make_float2(wA1.x, wA1.y), make_float2(wA1.z, wA1.w)};
    float2 wb[4] = {make_float2(wB0.x, wB0.y), make_float2(wB0.z, wB0.w),
                    make_float2(wB1.x, wB1.y), make_float2(wB1.z, wB1.w)};
    #pragma unroll
    for (int r = 0; r < 8; ++r) {
      float2 xv = *(const float2*)&xrow[r * 128 + d];
      #pragma unroll
      for (int c = 0; c < 4; ++c) {
        E2[r][c] = pkfma(make_float2(xv.x, xv.x), wa[c], E2[r][c]);
        E2[r][c] = pkfma(make_float2(xv.y, xv.y), wb[c], E2[r][c]);
      }
    }
  }
  #pragma unroll
  for (int r = 0; r < 8; ++r)
    #pragma unroll
    for (int c = 0; c < 4; ++c) {
      E2[r][c].x = __expf(E2[r][c].x);
      E2[r][c].y = __expf(E2[r][c].y);
    }
  __syncthreads();  // wt dead; cw may now be written

  // ---- Phase 2: 100 Sinkhorn iterations ----
  float ur[8];  // eu for this thread's 8 rows (kept in regs)
  float2 ep[4];
  for (int it = 0; it < 100; ++it) {
    float4 e0 = *(const float4*)&ev[8 * gj];
    float4 e1 = *(const float4*)&ev[8 * gj + 4];
    ep[0] = make_float2(e0.x, e0.y);
    ep[1] = make_float2(e0.z, e0.w);
    ep[2] = make_float2(e1.x, e1.y);
    ep[3] = make_float2(e1.z, e1.w);
    // (A) row sums via pk-dot + DPP butterfly over gj (xor 1,2,4)
    #pragma unroll
    for (int r = 0; r < 8; ++r) {
      float2 a = make_float2(0.f, 0.f);
      #pragma unroll
      for (int c = 0; c < 4; ++c) a = pkfma(E2[r][c], ep[c], a);
      float sr = a.x + a.y;
      sr = dpp_add<0xB1>(sr);
      sr = dpp_add<0x4E>(sr);
      sr = dpp_add<0x141>(sr);
      ur[r] = 0.0625f * __builtin_amdgcn_rcpf(sr);
    }
    // (B) column partials over this thread's 8 rows
    float2 tp[4] = {make_float2(0.f, 0.f), make_float2(0.f, 0.f),
                    make_float2(0.f, 0.f), make_float2(0.f, 0.f)};
    #pragma unroll
    for (int r = 0; r < 8; ++r) {
      float2 uu = make_float2(ur[r], ur[r]);
      #pragma unroll
      for (int c = 0; c < 4; ++c) tp[c] = pkfma(E2[r][c], uu, tp[c]);
    }
    float tv[8] = {tp[0].x, tp[0].y, tp[1].x, tp[1].y,
                   tp[2].x, tp[2].y, tp[3].x, tp[3].y};
    #pragma unroll
    for (int k = 0; k < 8; ++k) {
      tv[k] = dpp_add<0x128>(tv[k]);  // xor8
      tv[k] = swz16_add(tv[k]);       // xor16; xor32 folded into LDS stage
    }
    // writers: lanes 0..7 and 32..39 hold their 32-half's column partials
    if ((lane & 31) < 8) {
      int row = t >> 5;  // 2*wave + half, 0..31
      *(float4*)&u_.cw[row][8 * gj] = make_float4(tv[0], tv[1], tv[2], tv[3]);
      *(float4*)&u_.cw[row][8 * gj + 4] =
          make_float4(tv[4], tv[5], tv[6], tv[7]);
    }
    __syncthreads();
    // (C) reduce 32 half-wave partials -> ev
    if (t < 64) {
      float ss = 0.f;
      #pragma unroll
      for (int p = 0; p < 32; ++p) ss += u_.cw[p][t];
      ev[t] = __builtin_amdgcn_rcpf(ss);
    }
    __syncthreads();
  }

  // ---- Phase 3: T = EK * eu_i * ev_j, store f16 ----
  {
    float4 e0 = *(const float4*)&ev[8 * gj];
    float4 e1 = *(const float4*)&ev[8 * gj + 4];
    ep[0] = make_float2(e0.x, e0.y);
    ep[1] = make_float2(e0.z, e0.w);
    ep[2] = make_float2(e1.x, e1.y);
    ep[3] = make_float2(e1.z, e1.w);
  }
  __half* Tb = T + (size_t)b * 1024 * 64;
  #pragma unroll
  for (int r = 0; r < 8; ++r) {
    #pragma unroll
    for (int c = 0; c < 4; ++c) {
      float2 tvv;
      tvv.x = E2[r][c].x * ur[r] * ep[c].x;
      tvv.y = E2[r][c].y * ur[r] * ep[c].y;
      *(__half2*)&Tb[(size_t)(8 * gi + r) * 64 + 8 * gj + 2 * c] =
          __float22half2_rn(tvv);
    }
  }
}

// out[n][o][m*128+d] = sum_i T[b][i][o] * x[n][i][d]
__global__ __launch_bounds__(512) void output_kernel(
    const float* __restrict__ x, const __half* __restrict__ T,
    float* __restrict__ out) {
  const int b = blockIdx.x;
  const int nb = b >> 2;
  const int m = b & 3;
  const int t = threadIdx.x;
  const int lane = t & 63, wv = t >> 6;
  const int og = t & 15;         // o = 4*og + oc
  const int db = (t >> 4) & 15;  // d = 8*db + ...
  const int s = t >> 8;          // i-half split

  __shared__ float Xbuf[2][32 * 128];   // 2 x 16 KB
  __shared__ __half Tbuf[2][32 * 64];   // 2 x 4 KB

  const float* xb = x + (size_t)nb * 1024 * 128;
  const __half* Tb = T + (size_t)b * 1024 * 64;

  float2 acc[4][4];
  #pragma unroll
  for (int oc = 0; oc < 4; ++oc)
    #pragma unroll
    for (int dp = 0; dp < 4; ++dp) acc[oc][dp] = make_float2(0.f, 0.f);

  // prefetch chunk 0
  {
    const float* xs = xb;
    for (int k = wv; k < 16; k += 8)
      gll16(xs + k * 256 + lane * 4, &Xbuf[0][k * 256]);
    if (wv < 4) gll16(Tb + wv * 512 + lane * 8, &Tbuf[0][wv * 512]);
  }

  for (int ch = 0; ch < 32; ++ch) {
    const int p = ch & 1;
    __syncthreads();  // drains this chunk's async loads (vmcnt(0) + barrier)
    if (ch + 1 < 32) {
      const float* xs = xb + (size_t)(ch + 1) * 4096;
      const __half* ts = Tb + (size_t)(ch + 1) * 2048;
      for (int k = wv; k < 16; k += 8)
        gll16(xs + k * 256 + lane * 4, &Xbuf[p ^ 1][k * 256]);
      if (wv < 4) gll16(ts + wv * 512 + lane * 8, &Tbuf[p ^ 1][wv * 512]);
    }
    #pragma unroll 4
    for (int ii = 0; ii < 16; ++ii) {
      const int i = 16 * s + ii;
      __half2 t01 = *(const __half2*)&Tbuf[p][i * 64 + 4 * og];
      __half2 t23 = *(const __half2*)&Tbuf[p][i * 64 + 4 * og + 2];
      float2 f01 = __half22float2(t01), f23 = __half22float2(t23);
      float to[4] = {f01.x, f01.y, f23.x, f23.y};
      float4 x0 = *(const float4*)&Xbuf[p][i * 128 + 8 * db];
      float4 x1 = *(const float4*)&Xbuf[p][i * 128 + 8 * db + 4];
      float2 xp[4] = {make_float2(x0.x, x0.y), make_float2(x0.z, x0.w),
                      make_float2(x1.x, x1.y), make_float2(x1.z, x1.w)};
      #pragma unroll
      for (int oc = 0; oc < 4; ++oc)
        #pragma unroll
        for (int dp = 0; dp < 4; ++dp)
          acc[oc][dp] =
              pkfma(make_float2(to[oc], to[oc]), xp[dp], acc[oc][dp]);
    }
  }

  // merge s=1 into s=0 via LDS (transposed layout: conflict-free), store
  __syncthreads();
  float2* mbuf = (float2*)&Xbuf[0][0];  // 16 x 256 float2 = 32 KB
  if (s == 1) {
    #pragma unroll
    for (int oc = 0; oc < 4; ++oc)
      #pragma unroll
      for (int dp = 0; dp < 4; ++dp)
        mbuf[(oc * 4 + dp) * 256 + (t - 256)] = acc[oc][dp];
  }
  __syncthreads();
  if (s == 0) {
    #pragma unroll
    for (int oc = 0; oc < 4; ++oc) {
      float2 p0 = mbuf[(oc * 4 + 0) * 256 + t];
      float2 p1 = mbuf[(oc * 4 + 1) * 256 + t];
      float2 p2 = mbuf[(oc * 4 + 2) * 256 + t];
      float2 p3 = mbuf[(oc * 4 + 3) * 256 + t];
      int o = 4 * og + oc;
      float* op = out + ((size_t)nb * 64 + o) * 512 + m * 128 + 8 * db;
      float4 o0 = make_float4(acc[oc][0].x + p0.x, acc[oc][0].y + p0.y,
                              acc[oc][1].x + p1.x, acc[oc][1].y + p1.y);
      float4 o1 = make_float4(acc[oc][2].x + p2.x, acc[oc][2].y + p2.y,
                              acc[oc][3].x + p3.x, acc[oc][3].y + p3.y);
      *(float4*)op = o0;
      *(float4*)(op + 4) = o1;
    }
  }
}

extern "C" void kernel_launch(void* const* d_in, const int* in_sizes, int n_in,
                              void* d_out, int out_size, void* d_ws, size_t ws_size,
                              hipStream_t stream) {
  const float* x = (const float*)d_in[0];  // [64][1024][128] fp32
  const float* w = (const float*)d_in[1];  // [4][64][128] fp32
  float* out = (float*)d_out;              // [64][64][512] fp32
  __half* T = (__half*)d_ws;               // 256*1024*64 f16 = 33.5 MB
  sinkhorn_kernel<<<256, 1024, 0, stream>>>(x, w, T);
  output_kernel<<<256, 512, 0, stream>>>(x, T, out);
}

// Round 3
// 205.061 us; speedup vs baseline: 2.1163x; 1.7689x over previous
//
#include <hip/hip_runtime.h>
#include <hip/hip_fp16.h>

// Sinkhorn OT. n=64, in_size=1024, in_dim=128, heads=4, out_size=64.
// kernel1: K-GEMM -> EK=exp(K) in regs (8x8/thread) -> multiplicative Sinkhorn
//   iters (DPP/swizzle reductions, 2 barriers/iter) with early convergence
//   exit (tol 1e-4 on v-residual; cap 100) -> T=EK*eu*ev f16 to d_ws.
// kernel2: out = T^T x per batch; 8o x 8d per-thread tile, i%4 segments,
//   global_load_lds double-buffered staging, LDS merge.
// Both use the same XCD-aware (nb,m) map so x + T stay in one XCD's L2.

__device__ __forceinline__ float2 pkfma(float2 a, float2 b, float2 c) {
  return make_float2(fmaf(a.x, b.x, c.x), fmaf(a.y, b.y, c.y));
}

template <int CTRL>
__device__ __forceinline__ float dpp_add(float v) {
  return v + __int_as_float(__builtin_amdgcn_update_dpp(
                 0, __float_as_int(v), CTRL, 0xf, 0xf, true));
}
__device__ __forceinline__ float swz16_add(float v) {
  return v + __int_as_float(
                 __builtin_amdgcn_ds_swizzle(__float_as_int(v), 0x401F));
}
__device__ __forceinline__ void gll16(const void* gsrc, void* ldst) {
  __builtin_amdgcn_global_load_lds(
      (const __attribute__((address_space(1))) void*)gsrc,
      (__attribute__((address_space(3))) void*)ldst, 16, 0, 0);
}

// XCD-aware batch map: 4 heads of one nb + 8 nb per XCD (4 MB x-slice = L2).
__device__ __forceinline__ void batch_map(int bb, int& nb, int& m) {
  int k = bb >> 3;
  nb = 8 * (bb & 7) + (k >> 2);
  m = k & 3;
}

__global__ __launch_bounds__(1024, 4) void sinkhorn_kernel(
    const float* __restrict__ x, const float* __restrict__ w,
    __half* __restrict__ T) {
  int nb, m;
  batch_map(blockIdx.x, nb, m);
  const int b = nb * 4 + m;
  const int t = threadIdx.x;
  const int gi = t >> 3;  // rows 8*gi..8*gi+7
  const int gj = t & 7;   // cols 8*gj..8*gj+7
  const int lane = t & 63;

  __shared__ union {
    float wt[128][68];  // phase 1 only
    float cw[32][68];   // col partials; stride 68 -> writer lanes conflict-free
  } u_;
  __shared__ float ev[64];
  __shared__ int cflag;

  // ---- Phase 1a: stage W^T ----
  const float* wm = w + (size_t)m * 64 * 128;
  for (int e = t; e < 64 * 128; e += 1024) {
    int j = e >> 7, d = e & 127;
    u_.wt[d][j] = wm[e];
  }
  if (t < 64) ev[t] = 1.0f;
  __syncthreads();

  // ---- Phase 1b: K tile, EK = exp(K); float4 x loads ----
  float2 E2[8][4];
  #pragma unroll
  for (int r = 0; r < 8; ++r)
    #pragma unroll
    for (int c = 0; c < 4; ++c) E2[r][c] = make_float2(0.f, 0.f);

  const float* xrow = x + (size_t)nb * 1024 * 128 + (size_t)gi * 8 * 128;
  for (int d = 0; d < 128; d += 4) {
    float2 wr[4][4];
    #pragma unroll
    for (int dd = 0; dd < 4; ++dd) {
      float4 a0 = *(const float4*)&u_.wt[d + dd][8 * gj];
      float4 a1 = *(const float4*)&u_.wt[d + dd][8 * gj + 4];
      wr[dd][0] = make_float2(a0.x, a0.y);
      wr[dd][1] = make_float2(a0.z, a0.w);
      wr[dd][2] = make_float2(a1.x, a1.y);
      wr[dd][3] = make_float2(a1.z, a1.w);
    }
    #pragma unroll
    for (int r = 0; r < 8; ++r) {
      float4 xv = *(const float4*)&xrow[r * 128 + d];
      float xs[4] = {xv.x, xv.y, xv.z, xv.w};
      #pragma unroll
      for (int dd = 0; dd < 4; ++dd)
        #pragma unroll
        for (int c = 0; c < 4; ++c)
          E2[r][c] =
              pkfma(make_float2(xs[dd], xs[dd]), wr[dd][c], E2[r][c]);
    }
  }
  #pragma unroll
  for (int r = 0; r < 8; ++r)
    #pragma unroll
    for (int c = 0; c < 4; ++c) {
      E2[r][c].x = __expf(E2[r][c].x);
      E2[r][c].y = __expf(E2[r][c].y);
    }
  __syncthreads();

  // ---- Phase 2: Sinkhorn iterations, early exit on convergence ----
  float ur[8];
  float2 ep[4];
  for (int it = 0; it < 100; ++it) {
    float4 e0 = *(const float4*)&ev[8 * gj];
    float4 e1 = *(const float4*)&ev[8 * gj + 4];
    ep[0] = make_float2(e0.x, e0.y);
    ep[1] = make_float2(e0.z, e0.w);
    ep[2] = make_float2(e1.x, e1.y);
    ep[3] = make_float2(e1.z, e1.w);
    // (A) row sums + DPP butterfly over gj
    #pragma unroll
    for (int r = 0; r < 8; ++r) {
      float2 a = make_float2(0.f, 0.f);
      #pragma unroll
      for (int c = 0; c < 4; ++c) a = pkfma(E2[r][c], ep[c], a);
      float sr = a.x + a.y;
      sr = dpp_add<0xB1>(sr);
      sr = dpp_add<0x4E>(sr);
      sr = dpp_add<0x141>(sr);
      ur[r] = 0.0625f * __builtin_amdgcn_rcpf(sr);
    }
    // (B) col partials over 8 rows, reduce xor8 (DPP) + xor16 (swizzle)
    float2 tp[4] = {make_float2(0.f, 0.f), make_float2(0.f, 0.f),
                    make_float2(0.f, 0.f), make_float2(0.f, 0.f)};
    #pragma unroll
    for (int r = 0; r < 8; ++r) {
      float2 uu = make_float2(ur[r], ur[r]);
      #pragma unroll
      for (int c = 0; c < 4; ++c) tp[c] = pkfma(E2[r][c], uu, tp[c]);
    }
    float tv[8] = {tp[0].x, tp[0].y, tp[1].x, tp[1].y,
                   tp[2].x, tp[2].y, tp[3].x, tp[3].y};
    #pragma unroll
    for (int k = 0; k < 8; ++k) {
      tv[k] = dpp_add<0x128>(tv[k]);
      tv[k] = swz16_add(tv[k]);
    }
    if ((lane & 31) < 8) {
      int row = t >> 5;
      *(float4*)&u_.cw[row][8 * gj] = make_float4(tv[0], tv[1], tv[2], tv[3]);
      *(float4*)&u_.cw[row][8 * gj + 4] =
          make_float4(tv[4], tv[5], tv[6], tv[7]);
    }
    __syncthreads();
    // (C) final reduce + convergence check (wave 0)
    if (t < 64) {
      float ss = 0.f;
      #pragma unroll
      for (int p = 0; p < 32; ++p) ss += u_.cw[p][t];
      float evo = ev[t];
      ev[t] = __builtin_amdgcn_rcpf(ss);
      unsigned long long bad = __ballot(fabsf(fmaf(ss, evo, -1.0f)) > 1e-4f);
      if (t == 0) cflag = (bad == 0ULL);
    }
    __syncthreads();
    if (cflag) break;
  }

  // ---- Phase 3: T = EK * eu_i * ev_j ----
  {
    float4 e0 = *(const float4*)&ev[8 * gj];
    float4 e1 = *(const float4*)&ev[8 * gj + 4];
    ep[0] = make_float2(e0.x, e0.y);
    ep[1] = make_float2(e0.z, e0.w);
    ep[2] = make_float2(e1.x, e1.y);
    ep[3] = make_float2(e1.z, e1.w);
  }
  __half* Tb = T + (size_t)b * 1024 * 64;
  #pragma unroll
  for (int r = 0; r < 8; ++r) {
    #pragma unroll
    for (int c = 0; c < 4; ++c) {
      float2 tvv;
      tvv.x = E2[r][c].x * ur[r] * ep[c].x;
      tvv.y = E2[r][c].y * ur[r] * ep[c].y;
      *(__half2*)&Tb[(size_t)(8 * gi + r) * 64 + 8 * gj + 2 * c] =
          __float22half2_rn(tvv);
    }
  }
}

// out[n][o][m*128+d] = sum_i T[b][i][o] * x[n][i][d]
// 512 thr: seg s = t>>7 handles i%4==s; r=t&127: og=r>>4 (8 o's), dg=r&15
// (d in {4dg..4dg+3} and {64+4dg..64+4dg+3}).
__global__ __launch_bounds__(512) void output_kernel(
    const float* __restrict__ x, const __half* __restrict__ T,
    float* __restrict__ out) {
  int nb, m;
  batch_map(blockIdx.x, nb, m);
  const int b = nb * 4 + m;
  const int t = threadIdx.x;
  const int lane = t & 63, wv = t >> 6;
  const int s = t >> 7;
  const int r = t & 127;
  const int og = r >> 4;
  const int dg = r & 15;

  __shared__ union {
    struct {
      float X[2][32 * 128];   // 2 x 16 KB
      __half Tc[2][32 * 64];  // 2 x 4 KB
    } st;
    float2 mg[2][4096];  // 64 KB merge space
  } u_;

  const float* xb = x + (size_t)nb * 1024 * 128;
  const __half* Tb = T + (size_t)b * 1024 * 64;

  float2 acc[8][4];
  #pragma unroll
  for (int oc = 0; oc < 8; ++oc)
    #pragma unroll
    for (int j = 0; j < 4; ++j) acc[oc][j] = make_float2(0.f, 0.f);

  // prefetch chunk 0
  {
    const float* xs = xb;
    gll16(xs + wv * 256 + lane * 4, &u_.st.X[0][wv * 256]);
    gll16(xs + (wv + 8) * 256 + lane * 4, &u_.st.X[0][(wv + 8) * 256]);
    if (wv < 4) gll16(Tb + wv * 512 + lane * 8, &u_.st.Tc[0][wv * 512]);
  }

  for (int ch = 0; ch < 32; ++ch) {
    const int p = ch & 1;
    __syncthreads();
    if (ch + 1 < 32) {
      const float* xs = xb + (size_t)(ch + 1) * 4096;
      const __half* ts = Tb + (size_t)(ch + 1) * 2048;
      gll16(xs + wv * 256 + lane * 4, &u_.st.X[p ^ 1][wv * 256]);
      gll16(xs + (wv + 8) * 256 + lane * 4, &u_.st.X[p ^ 1][(wv + 8) * 256]);
      if (wv < 4) gll16(ts + wv * 512 + lane * 8, &u_.st.Tc[p ^ 1][wv * 512]);
    }
    #pragma unroll
    for (int kk = 0; kk < 8; ++kk) {
      const int i = 4 * kk + s;
      float4 xa = *(const float4*)&u_.st.X[p][i * 128 + 4 * dg];
      float4 xc = *(const float4*)&u_.st.X[p][i * 128 + 64 + 4 * dg];
      float4 tv4 = *(const float4*)&u_.st.Tc[p][i * 64 + 8 * og];
      const __half2* th = (const __half2*)&tv4;
      float2 tf0 = __half22float2(th[0]), tf1 = __half22float2(th[1]);
      float2 tf2 = __half22float2(th[2]), tf3 = __half22float2(th[3]);
      float to[8] = {tf0.x, tf0.y, tf1.x, tf1.y,
                     tf2.x, tf2.y, tf3.x, tf3.y};
      float2 xp[4] = {make_float2(xa.x, xa.y), make_float2(xa.z, xa.w),
                      make_float2(xc.x, xc.y), make_float2(xc.z, xc.w)};
      #pragma unroll
      for (int oc = 0; oc < 8; ++oc) {
        float2 tt = make_float2(to[oc], to[oc]);
        #pragma unroll
        for (int j = 0; j < 4; ++j)
          acc[oc][j] = pkfma(tt, xp[j], acc[oc][j]);
      }
    }
  }

  // merge 4 segments -> seg 0, then store
  __syncthreads();
  if (s & 1) {  // segs 1,3 write
    float2* mp = u_.mg[s >> 1];
    #pragma unroll
    for (int oc = 0; oc < 8; ++oc)
      #pragma unroll
      for (int j = 0; j < 4; ++j) mp[(oc * 4 + j) * 128 + r] = acc[oc][j];
  }
  __syncthreads();
  if (!(s & 1)) {  // segs 0,2 add
    const float2* mp = u_.mg[s >> 1];
    #pragma unroll
    for (int oc = 0; oc < 8; ++oc)
      #pragma unroll
      for (int j = 0; j < 4; ++j) {
        float2 v = mp[(oc * 4 + j) * 128 + r];
        acc[oc][j].x += v.x;
        acc[oc][j].y += v.y;
      }
  }
  __syncthreads();
  if (s == 2) {
    float2* mp = u_.mg[0];
    #pragma unroll
    for (int oc = 0; oc < 8; ++oc)
      #pragma unroll
      for (int j = 0; j < 4; ++j) mp[(oc * 4 + j) * 128 + r] = acc[oc][j];
  }
  __syncthreads();
  if (s == 0) {
    const float2* mp = u_.mg[0];
    #pragma unroll
    for (int oc = 0; oc < 8; ++oc) {
      float2 p0 = mp[(oc * 4 + 0) * 128 + r];
      float2 p1 = mp[(oc * 4 + 1) * 128 + r];
      float2 p2 = mp[(oc * 4 + 2) * 128 + r];
      float2 p3 = mp[(oc * 4 + 3) * 128 + r];
      int o = 8 * og + oc;
      float* op = out + ((size_t)nb * 64 + o) * 512 + m * 128;
      float4 s0 = make_float4(acc[oc][0].x + p0.x, acc[oc][0].y + p0.y,
                              acc[oc][1].x + p1.x, acc[oc][1].y + p1.y);
      float4 s1 = make_float4(acc[oc][2].x + p2.x, acc[oc][2].y + p2.y,
                              acc[oc][3].x + p3.x, acc[oc][3].y + p3.y);
      *(float4*)(op + 4 * dg) = s0;
      *(float4*)(op + 64 + 4 * dg) = s1;
    }
  }
}

extern "C" void kernel_launch(void* const* d_in, const int* in_sizes, int n_in,
                              void* d_out, int out_size, void* d_ws, size_t ws_size,
                              hipStream_t stream) {
  const float* x = (const float*)d_in[0];  // [64][1024][128] fp32
  const float* w = (const float*)d_in[1];  // [4][64][128] fp32
  float* out = (float*)d_out;              // [64][64][512] fp32
  __half* T = (__half*)d_ws;               // 256*1024*64 f16 = 33.5 MB
  sinkhorn_kernel<<<256, 1024, 0, stream>>>(x, w, T);
  output_kernel<<<256, 512, 0, stream>>>(x, T, out);
}